// Round 12
// baseline (395.721 us; speedup 1.0000x reference)
//
#include <hip/hip_runtime.h>

#define T_TOK 2048
#define H_DIM 1024
#define I_DIM 2048
#define SHBASE 4096              // T*K expert slots; shared slots follow
#define KN_PANEL (1024 * 2048)   // elements per weight panel (both shapes)

typedef short short8 __attribute__((ext_vector_type(8)));
typedef float floatx4 __attribute__((ext_vector_type(4)));

#define WAITVM(N) asm volatile("s_waitcnt vmcnt(" #N ")" ::: "memory")
#define LGKM0()   asm volatile("s_waitcnt lgkmcnt(0)" ::: "memory")
#define SCHEDB()  __builtin_amdgcn_sched_barrier(0)
#define BARRIER() do { SCHEDB(); __builtin_amdgcn_s_barrier(); SCHEDB(); } while (0)

__device__ __forceinline__ unsigned short f2bf(float f) {
  unsigned int u = __builtin_bit_cast(unsigned int, f);
  u += 0x7FFFu + ((u >> 16) & 1u);
  return (unsigned short)(u >> 16);
}
__device__ __forceinline__ float bf2f(unsigned short u) {
  return __builtin_bit_cast(float, (unsigned int)u << 16);
}
__device__ __forceinline__ unsigned int cvtpk(float lo, float hi) {
  unsigned int r;
  asm("v_cvt_pk_bf16_f32 %0, %1, %2" : "=v"(r) : "v"(lo), "v"(hi));
  return r;
}
__device__ __forceinline__ void gl16(const void* g, void* l) {
  __builtin_amdgcn_global_load_lds(
      (const __attribute__((address_space(1))) unsigned int*)g,
      (__attribute__((address_space(3))) unsigned int*)l, 16, 0, 0);
}

// LDS tile layout: 128 rows(cols) x 32 k bf16 = 512 x 16B chunks, oct-major
// linear: chunk(r, o) = o*128 + r. Fragment ds_read_b128 conflict-free.

// ---------------------------------------------------------------- gate
__global__ __launch_bounds__(256) void gate_kernel(
    const float* __restrict__ x, const float* __restrict__ gw,
    unsigned short* __restrict__ xb, int* __restrict__ cnt,
    int4* __restrict__ rec, float2* __restrict__ wrec)
{
  __shared__ float red[8][4];
  int t = blockIdx.x;
  int tid = threadIdx.x;
  const float* xr = x + (size_t)t * H_DIM;
  float xv[4];
#pragma unroll
  for (int j = 0; j < 4; ++j) {
    int h = tid + j * 256;
    xv[j] = xr[h];
    xb[(size_t)t * H_DIM + h] = f2bf(xv[j]);
  }
  float p[8];
#pragma unroll
  for (int e = 0; e < 8; ++e) {
    const float* gptr = gw + e * H_DIM;
    float s = 0.f;
#pragma unroll
    for (int j = 0; j < 4; ++j) s += xv[j] * gptr[tid + j * 256];
    p[e] = s;
  }
  int lane = tid & 63, wv = tid >> 6;
#pragma unroll
  for (int e = 0; e < 8; ++e) {
    float s = p[e];
#pragma unroll
    for (int off = 32; off > 0; off >>= 1) s += __shfl_down(s, off);
    if (lane == 0) red[e][wv] = s;
  }
  __syncthreads();
  if (tid == 0) {
    float sc[8], pr[8];
    float m = -1e30f;
#pragma unroll
    for (int e = 0; e < 8; ++e) {
      sc[e] = red[e][0] + red[e][1] + red[e][2] + red[e][3];
      m = fmaxf(m, sc[e]);
    }
    float Z = 0.f;
#pragma unroll
    for (int e = 0; e < 8; ++e) { pr[e] = __expf(sc[e] - m); Z += pr[e]; }
#pragma unroll
    for (int e = 0; e < 8; ++e) pr[e] /= Z;
    int i0 = 0;
#pragma unroll
    for (int e = 1; e < 8; ++e) if (pr[e] > pr[i0]) i0 = e;
    int i1 = (i0 == 0) ? 1 : 0;
#pragma unroll
    for (int e = 0; e < 8; ++e) if (e != i0 && pr[e] > pr[i1]) i1 = e;
    float w0 = pr[i0], w1_ = pr[i1];
    float s2 = w0 + w1_ + 1e-20f;
    w0 /= s2; w1_ /= s2;
    int p0 = atomicAdd(&cnt[i0], 1);
    int p1 = atomicAdd(&cnt[i1], 1);
    rec[t] = make_int4(i0, i1, p0, p1);
    wrec[t] = make_float2(w0, w1_);
  }
}

// ---------------------------------------------------------------- scatter
__global__ __launch_bounds__(256) void scatter_kernel(
    const int* __restrict__ cnt, const int4* __restrict__ rec,
    int* __restrict__ tok, int2* __restrict__ slots)
{
  int t = blockIdx.x * 256 + threadIdx.x;
  if (t >= T_TOK) return;
  int bases[8];
  int b = 0;
#pragma unroll
  for (int e = 0; e < 8; ++e) { bases[e] = b; b += cnt[e]; }
  int4 r = rec[t];
  int s0 = bases[r.x] + r.z;
  int s1 = bases[r.y] + r.w;
  tok[s0] = t;
  tok[s1] = t;
  tok[SHBASE + t] = t;
  slots[t] = make_int2(s0, s1);
}

// ---------------------------------------------------------------- up GEMM
// 128r x 128c, BK=32, 8 waves (2Mx4N). fp32 weights loaded directly:
// reg-staged depth-2 (2 named sets), cvt_pk -> bf16 ds_write, A via gl16 DMA
// (3 LDS bufs). Raw barriers + counted vmcnt; no image pass.
__global__ __launch_bounds__(512, 4) void ffn_up(
    const unsigned short* __restrict__ xb,
    const float* __restrict__ w1, const float* __restrict__ w3,
    const float* __restrict__ sw1, const float* __restrict__ sw3,
    const int* __restrict__ cnt, const int* __restrict__ tok,
    unsigned short* __restrict__ act)
{
  int z = blockIdx.z;
  int base = 0;
#pragma unroll
  for (int e = 0; e < 8; ++e) if (e < z || z == 8) base += cnt[e];
  int nrows = (z == 8) ? T_TOK : cnt[z];
  int row0 = blockIdx.y * 128;
  if (row0 >= nrows) return;
  int nt = blockIdx.x;
  const float* W1 = (z < 8) ? w1 + (size_t)z * KN_PANEL : sw1;
  const float* W3 = (z < 8) ? w3 + (size_t)z * KN_PANEL : sw3;

  __shared__ unsigned short A[3][4096];
  __shared__ unsigned short B1[2][4096];
  __shared__ unsigned short B3[2][4096];

  const int tid = threadIdx.x;
  const int lane = tid & 63, wv = tid >> 6;
  const int l16 = lane & 15, g = lane >> 4;
  const int wr = wv >> 2, wc = wv & 3;

  // A staging (DMA)
  int ao = tid >> 7, ar = tid & 127;
  int grow = row0 + ar;
  if (grow >= nrows) grow = nrows - 1;
  const unsigned short* pA = xb + (size_t)tok[base + grow] * H_DIM + ao * 8;

  // B staging (reg): thread -> (col bc, k-oct bo)
  const int bc = tid & 127, bo = tid >> 7;
  const float* pB1 = W1 + (size_t)(bo * 8) * I_DIM + nt * 128 + bc;
  const float* pB3 = W3 + (size_t)(bo * 8) * I_DIM + nt * 128 + bc;
  const int bix = (bo * 128 + bc) * 8;

  int ach[4], bch[2];
#pragma unroll
  for (int m = 0; m < 4; ++m) ach[m] = (g * 128 + wr * 64 + m * 16 + l16) * 8;
#pragma unroll
  for (int n = 0; n < 2; ++n) bch[n] = (g * 128 + wc * 32 + n * 16 + l16) * 8;

  floatx4 acc1[4][2], acc3[4][2];
#pragma unroll
  for (int m = 0; m < 4; ++m)
#pragma unroll
    for (int n = 0; n < 2; ++n) { acc1[m][n] = (floatx4)0.f; acc3[m][n] = (floatx4)0.f; }

  float s1a[8], s3a[8], s1b[8], s3b[8];

#define UP_LOADB(S1, S3, KS) do { \
    const float* q1 = pB1 + (size_t)(KS) * 32 * I_DIM; \
    const float* q3 = pB3 + (size_t)(KS) * 32 * I_DIM; \
    _Pragma("unroll") \
    for (int j = 0; j < 8; ++j) { \
      S1[j] = q1[(size_t)j * I_DIM]; S3[j] = q3[(size_t)j * I_DIM]; } } while (0)

#define UP_WRITEB(S1, S3, BUF) do { \
    uint4 u1, u3; \
    u1.x = cvtpk(S1[0], S1[1]); u1.y = cvtpk(S1[2], S1[3]); \
    u1.z = cvtpk(S1[4], S1[5]); u1.w = cvtpk(S1[6], S1[7]); \
    u3.x = cvtpk(S3[0], S3[1]); u3.y = cvtpk(S3[2], S3[3]); \
    u3.z = cvtpk(S3[4], S3[5]); u3.w = cvtpk(S3[6], S3[7]); \
    *(uint4*)&B1[BUF][bix] = u1; *(uint4*)&B3[BUF][bix] = u3; } while (0)

  auto stageA = [&](int buf, int ks) { gl16(pA + ks * 32, &A[buf][wv * 512]); };

  auto compute = [&](int ab, int bb) {
    short8 af[4];
#pragma unroll
    for (int m = 0; m < 4; ++m) af[m] = *(const short8*)&A[ab][ach[m]];
#pragma unroll
    for (int n = 0; n < 2; ++n) {
      short8 b1 = *(const short8*)&B1[bb][bch[n]];
      short8 b3 = *(const short8*)&B3[bb][bch[n]];
#pragma unroll
      for (int m = 0; m < 4; ++m) {
        acc1[m][n] = __builtin_amdgcn_mfma_f32_16x16x32_bf16(af[m], b1, acc1[m][n], 0, 0, 0);
        acc3[m][n] = __builtin_amdgcn_mfma_f32_16x16x32_bf16(af[m], b3, acc3[m][n], 0, 0, 0);
      }
    }
  };

  const int NT = H_DIM / 32;                 // 32 (even)
  // prologue: sets for steps 0 (a), 1 (b); make buf0 ready; reload a <- 2
  stageA(0, 0); UP_LOADB(s1a, s3a, 0);       // 17 vmem
  stageA(1, 1); UP_LOADB(s1b, s3b, 1);       // 17 vmem
  WAITVM(17); SCHEDB();
  UP_WRITEB(s1a, s3a, 0);
  stageA(2, 2); UP_LOADB(s1a, s3a, 2);
  LGKM0(); BARRIER();

  int ab = 0;
#pragma unroll 1
  for (int ks = 0; ks < NT; ks += 2) {
    // even step: B buf 0; trailing readies step ks+1 (set b)
    __builtin_amdgcn_s_setprio(1);
    compute(ab, 0);
    __builtin_amdgcn_s_setprio(0); SCHEDB();
    BARRIER();
    WAITVM(17); SCHEDB();
    UP_WRITEB(s1b, s3b, 1);
    int t3 = (ks + 3 < NT) ? ks + 3 : NT - 1;
    stageA(ab, t3); UP_LOADB(s1b, s3b, t3);
    LGKM0(); BARRIER();
    int ab1 = (ab == 2) ? 0 : ab + 1;
    // odd step: B buf 1; trailing readies step ks+2 (set a)
    __builtin_amdgcn_s_setprio(1);
    compute(ab1, 1);
    __builtin_amdgcn_s_setprio(0); SCHEDB();
    if (ks + 2 < NT) {
      BARRIER();
      WAITVM(17); SCHEDB();
      UP_WRITEB(s1a, s3a, 0);
      int t4 = (ks + 4 < NT) ? ks + 4 : NT - 1;
      stageA(ab1, t4); UP_LOADB(s1a, s3a, t4);
      LGKM0(); BARRIER();
    }
    ab = (ab1 == 2) ? 0 : ab1 + 1;
  }
  WAITVM(0);   // drain pad DMA before LDS dealloc

#pragma unroll
  for (int m = 0; m < 4; ++m) {
    int rl = wr * 64 + m * 16 + g * 4;
#pragma unroll
    for (int n = 0; n < 2; ++n) {
      int col = nt * 128 + wc * 32 + n * 16 + l16;
#pragma unroll
      for (int r = 0; r < 4; ++r) {
        int row = rl + r;
        if (row0 + row < nrows) {
          float h1 = acc1[m][n][r], h3 = acc3[m][n][r];
          float a = h1 / (1.0f + __expf(-h1)) * h3;
          act[(size_t)(base + row0 + row) * I_DIM + col] = f2bf(a);
        }
      }
    }
  }
#undef UP_LOADB
#undef UP_WRITEB
}

// ---------------------------------------------------------------- down GEMM
__global__ __launch_bounds__(512, 4) void ffn_down(
    const unsigned short* __restrict__ act,
    const float* __restrict__ w2, const float* __restrict__ sw2,
    const int* __restrict__ cnt, unsigned short* __restrict__ yslot)
{
  int z = blockIdx.z;
  int base = 0;
#pragma unroll
  for (int e = 0; e < 8; ++e) if (e < z || z == 8) base += cnt[e];
  int nrows = (z == 8) ? T_TOK : cnt[z];
  int row0 = blockIdx.y * 128;
  if (row0 >= nrows) return;
  int nt = blockIdx.x;
  const float* W2 = (z < 8) ? w2 + (size_t)z * KN_PANEL : sw2;

  __shared__ unsigned short A[3][4096];
  __shared__ unsigned short B[2][4096];

  const int tid = threadIdx.x;
  const int lane = tid & 63, wv = tid >> 6;
  const int l16 = lane & 15, g = lane >> 4;
  const int wr = wv >> 2, wc = wv & 3;

  int ao = tid >> 7, ar = tid & 127;
  int grow = row0 + ar;
  if (grow >= nrows) grow = nrows - 1;
  const unsigned short* pA = act + (size_t)(base + grow) * I_DIM + ao * 8;

  const int bc = tid & 127, bo = tid >> 7;
  const float* pB = W2 + (size_t)(bo * 8) * H_DIM + nt * 128 + bc;
  const int bix = (bo * 128 + bc) * 8;

  int ach[4], bch[2];
#pragma unroll
  for (int m = 0; m < 4; ++m) ach[m] = (g * 128 + wr * 64 + m * 16 + l16) * 8;
#pragma unroll
  for (int n = 0; n < 2; ++n) bch[n] = (g * 128 + wc * 32 + n * 16 + l16) * 8;

  floatx4 acc[4][2];
#pragma unroll
  for (int m = 0; m < 4; ++m)
#pragma unroll
    for (int n = 0; n < 2; ++n) acc[m][n] = (floatx4)0.f;

  float sa[8], sb[8];

#define DN_LOADB(S, KS) do { \
    const float* q = pB + (size_t)(KS) * 32 * H_DIM; \
    _Pragma("unroll") \
    for (int j = 0; j < 8; ++j) S[j] = q[(size_t)j * H_DIM]; } while (0)

#define DN_WRITEB(S, BUF) do { \
    uint4 u; \
    u.x = cvtpk(S[0], S[1]); u.y = cvtpk(S[2], S[3]); \
    u.z = cvtpk(S[4], S[5]); u.w = cvtpk(S[6], S[7]); \
    *(uint4*)&B[BUF][bix] = u; } while (0)

  auto stageA = [&](int buf, int ks) { gl16(pA + ks * 32, &A[buf][wv * 512]); };

  auto compute = [&](int ab, int bb) {
    short8 af[4];
#pragma unroll
    for (int m = 0; m < 4; ++m) af[m] = *(const short8*)&A[ab][ach[m]];
#pragma unroll
    for (int n = 0; n < 2; ++n) {
      short8 bfr = *(const short8*)&B[bb][bch[n]];
#pragma unroll
      for (int m = 0; m < 4; ++m)
        acc[m][n] = __builtin_amdgcn_mfma_f32_16x16x32_bf16(af[m], bfr, acc[m][n], 0, 0, 0);
    }
  };

  const int NT = I_DIM / 32;                 // 64 (even)
  stageA(0, 0); DN_LOADB(sa, 0);             // 9 vmem
  stageA(1, 1); DN_LOADB(sb, 1);             // 9 vmem
  WAITVM(9); SCHEDB();
  DN_WRITEB(sa, 0);
  stageA(2, 2); DN_LOADB(sa, 2);
  LGKM0(); BARRIER();

  int ab = 0;
#pragma unroll 1
  for (int ks = 0; ks < NT; ks += 2) {
    __builtin_amdgcn_s_setprio(1);
    compute(ab, 0);
    __builtin_amdgcn_s_setprio(0); SCHEDB();
    BARRIER();
    WAITVM(9); SCHEDB();
    DN_WRITEB(sb, 1);
    int t3 = (ks + 3 < NT) ? ks + 3 : NT - 1;
    stageA(ab, t3); DN_LOADB(sb, t3);
    LGKM0(); BARRIER();
    int ab1 = (ab == 2) ? 0 : ab + 1;
    __builtin_amdgcn_s_setprio(1);
    compute(ab1, 1);
    __builtin_amdgcn_s_setprio(0); SCHEDB();
    if (ks + 2 < NT) {
      BARRIER();
      WAITVM(9); SCHEDB();
      DN_WRITEB(sa, 0);
      int t4 = (ks + 4 < NT) ? ks + 4 : NT - 1;
      stageA(ab1, t4); DN_LOADB(sa, t4);
      LGKM0(); BARRIER();
    }
    ab = (ab1 == 2) ? 0 : ab1 + 1;
  }
  WAITVM(0);

#pragma unroll
  for (int m = 0; m < 4; ++m) {
    int rl = wr * 64 + m * 16 + g * 4;
#pragma unroll
    for (int n = 0; n < 2; ++n) {
      int col = nt * 128 + wc * 32 + n * 16 + l16;
#pragma unroll
      for (int r = 0; r < 4; ++r) {
        int row = rl + r;
        if (row0 + row < nrows)
          yslot[(size_t)(base + row0 + row) * H_DIM + col] = f2bf(acc[m][n][r]);
      }
    }
  }
#undef DN_LOADB
#undef DN_WRITEB
}

// ---------------------------------------------------------------- combine (4 tokens/block)
__global__ __launch_bounds__(256) void combine_kernel(
    const unsigned short* __restrict__ y, const int2* __restrict__ slots,
    const float2* __restrict__ wrec, float* __restrict__ out)
{
  int h = threadIdx.x * 4;
#pragma unroll
  for (int k = 0; k < 4; ++k) {
    int t = blockIdx.x * 4 + k;
    int2 s = slots[t];
    float2 w = wrec[t];
    ushort4 a = *(const ushort4*)&y[(size_t)s.x * H_DIM + h];
    ushort4 b = *(const ushort4*)&y[(size_t)s.y * H_DIM + h];
    ushort4 c = *(const ushort4*)&y[(size_t)(SHBASE + t) * H_DIM + h];
    floatx4 o;
    o[0] = bf2f(a.x) * w.x + bf2f(b.x) * w.y + bf2f(c.x);
    o[1] = bf2f(a.y) * w.x + bf2f(b.y) * w.y + bf2f(c.y);
    o[2] = bf2f(a.z) * w.x + bf2f(b.z) * w.y + bf2f(c.z);
    o[3] = bf2f(a.w) * w.x + bf2f(b.w) * w.y + bf2f(c.w);
    *(floatx4*)&out[(size_t)t * H_DIM + h] = o;
  }
}

// ---------------------------------------------------------------- launch
extern "C" void kernel_launch(void* const* d_in, const int* in_sizes, int n_in,
                              void* d_out, int out_size, void* d_ws, size_t ws_size,
                              hipStream_t stream) {
  const float* x   = (const float*)d_in[0];
  const float* gw  = (const float*)d_in[1];
  const float* w1  = (const float*)d_in[2];
  const float* w2  = (const float*)d_in[3];
  const float* w3  = (const float*)d_in[4];
  const float* sw1 = (const float*)d_in[5];
  const float* sw2 = (const float*)d_in[6];
  const float* sw3 = (const float*)d_in[7];
  float* out = (float*)d_out;

  char* ws = (char*)d_ws;
  int*            cnt   = (int*)ws;                            // 64 B
  int4*           rec   = (int4*)(ws + 1024);                  // 32 KB
  float2*         wrec  = (float2*)(ws + (64 << 10));          // 16 KB
  int*            tok   = (int*)(ws + (128 << 10));            // 24 KB
  int2*           slots = (int2*)(ws + (192 << 10));           // 16 KB
  unsigned short* xb    = (unsigned short*)(ws + (1 << 20));   // 4 MB
  unsigned short* act   = (unsigned short*)(ws + (8ull << 20));   // 24 MB
  unsigned short* yslot = (unsigned short*)(ws + (32ull << 20));  // 12 MB

  hipMemsetAsync(cnt, 0, 64, stream);

  gate_kernel<<<T_TOK, 256, 0, stream>>>(x, gw, xb, cnt, rec, wrec);
  scatter_kernel<<<T_TOK / 256, 256, 0, stream>>>(cnt, rec, tok, slots);
  ffn_up<<<dim3(I_DIM / 128, 16, 9), 512, 0, stream>>>(xb, w1, w3, sw1, sw3,
                                                       cnt, tok, act);
  ffn_down<<<dim3(H_DIM / 128, 16, 9), 512, 0, stream>>>(act, w2, sw2, cnt, yslot);
  combine_kernel<<<512, 256, 0, stream>>>(yslot, slots, wrec, out);
}